// Round 2
// baseline (295.450 us; speedup 1.0000x reference)
//
#include <hip/hip_runtime.h>
#include <hip/hip_cooperative_groups.h>

namespace cg = cooperative_groups;

// ---------------- quantum gate appliers (16-amp statevector in regs) ----------------
// wire w -> bit position (3 - w); bit 3 is MSB of the flat index (row-major reshape).

__device__ __forceinline__ void apply_rx(float* sr, float* si, int bit, float c, float s) {
    const int m = 1 << bit;
#pragma unroll
    for (int idx = 0; idx < 16; ++idx) {
        if (idx & m) continue;
        const int j = idx | m;
        float a0r = sr[idx], a0i = si[idx], a1r = sr[j], a1i = si[j];
        // U = [[c, -i s], [-i s, c]]
        sr[idx] = c * a0r + s * a1i;
        si[idx] = c * a0i - s * a1r;
        sr[j]   = c * a1r + s * a0i;
        si[j]   = c * a1i - s * a0r;
    }
}

__device__ __forceinline__ void apply_ry(float* sr, float* si, int bit, float c, float s) {
    const int m = 1 << bit;
#pragma unroll
    for (int idx = 0; idx < 16; ++idx) {
        if (idx & m) continue;
        const int j = idx | m;
        float a0r = sr[idx], a0i = si[idx], a1r = sr[j], a1i = si[j];
        // U = [[c, -s], [s, c]]
        sr[idx] = c * a0r - s * a1r;
        si[idx] = c * a0i - s * a1i;
        sr[j]   = s * a0r + c * a1r;
        si[j]   = s * a0i + c * a1i;
    }
}

__device__ __forceinline__ void apply_rz(float* sr, float* si, int bit, float c, float s) {
    const int m = 1 << bit;
#pragma unroll
    for (int idx = 0; idx < 16; ++idx) {
        if (idx & m) continue;
        const int j = idx | m;
        float a0r = sr[idx], a0i = si[idx], a1r = sr[j], a1i = si[j];
        // diag(e^{-i t/2}, e^{+i t/2}) ; c = cos(t/2), s = sin(t/2)
        sr[idx] = c * a0r + s * a0i;
        si[idx] = c * a0i - s * a0r;
        sr[j]   = c * a1r - s * a1i;
        si[j]   = c * a1i + s * a1r;
    }
}

__device__ __forceinline__ void apply_cnot(float* sr, float* si, int cw, int tw) {
    const int cb = 3 - cw, tb = 3 - tw;
#pragma unroll
    for (int idx = 0; idx < 16; ++idx) {
        if (((idx >> cb) & 1) && !((idx >> tb) & 1)) {
            const int j = idx | (1 << tb);
            float tr = sr[idx]; sr[idx] = sr[j]; sr[j] = tr;
            float ti = si[idx]; si[idx] = si[j]; si[j] = ti;
        }
    }
}

// ---------------- single fused cooperative kernel ----------------
// One thread per sample. 256 blocks x 256 threads = B = 65536 -> 1 block/CU,
// trivially co-resident for cooperative launch.
//
// Phase 1: per-thread stream of the sample's 2304 B (144 float4, sequential,
//          line-efficient) -> pooled[16] -> angles (enc_w via uniform s_loads)
//          -> circuit in registers -> z[4] kept in REGISTERS.
// Phase 2: block partials (sum z, sum z^2) -> grid.sync() -> every block
//          redundantly reduces the 8 KB partials from L2 -> BN applied to the
//          register-resident z -> single coalesced float4 store.
// Global traffic: 151 MB read + 1 MB write + ~16 KB partials. HBM floor ~24 us.

__global__ __launch_bounds__(256) void fused_kernel(
    const float4* __restrict__ x,           // fp32 x viewed as float4 (144 per sample)
    const float* __restrict__ enc_w,        // [4,16]
    const float* __restrict__ enc_b,        // [4]
    const float* __restrict__ var_params,   // [2,4,3] = 24
    const float* __restrict__ gamma,        // [4]
    const float* __restrict__ beta,         // [4]
    float4* __restrict__ out,               // [B] float4 (= d_out)
    float* __restrict__ partials,           // [gridDim.x * 8]
    int B)
{
    __shared__ float red[4 * 8];
    __shared__ float stats[8];

    const int t = threadIdx.x;
    const int s = blockIdx.x * 256 + t;

    // ---- pool: 6x6 mean, per-thread stream (all indices compile-time) ----
    float pooled[16];
#pragma unroll
    for (int i = 0; i < 16; ++i) pooled[i] = 0.0f;

    const float4* xs = x + (size_t)s * 144;
#pragma unroll
    for (int k = 0; k < 144; ++k) {
        const float4 v = xs[k];
        { const int f = 4 * k + 0, r = f / 24, c = f - 24 * r; pooled[(r / 6) * 4 + (c / 6)] += v.x; }
        { const int f = 4 * k + 1, r = f / 24, c = f - 24 * r; pooled[(r / 6) * 4 + (c / 6)] += v.y; }
        { const int f = 4 * k + 2, r = f / 24, c = f - 24 * r; pooled[(r / 6) * 4 + (c / 6)] += v.z; }
        { const int f = 4 * k + 3, r = f / 24, c = f - 24 * r; pooled[(r / 6) * 4 + (c / 6)] += v.w; }
    }
#pragma unroll
    for (int i = 0; i < 16; ++i) pooled[i] *= (1.0f / 36.0f);

    // ---- angles: enc_w/enc_b are wave-uniform -> scalar loads ----
    float av[4];
#pragma unroll
    for (int i = 0; i < 4; ++i) {
        float a = enc_b[i];
#pragma unroll
        for (int k = 0; k < 16; ++k)
            a += enc_w[i * 16 + k] * pooled[k];
        av[i] = a;
    }

    // ---- gate tables: uniform var_params -> s_loads; sincos in VALU ----
    float gc[24], gs[24];
#pragma unroll
    for (int i = 0; i < 24; ++i) {
        float sn, cs;
        __sincosf(0.5f * var_params[i], &sn, &cs);
        gc[i] = cs; gs[i] = sn;
    }

    // ---- statevector simulation, all in registers ----
    float sr[16], si[16];
#pragma unroll
    for (int i = 0; i < 16; ++i) { sr[i] = 0.0f; si[i] = 0.0f; }
    sr[0] = 1.0f;

#pragma unroll
    for (int w = 0; w < 4; ++w) {
        float sn, cs;
        __sincosf(0.5f * av[w], &sn, &cs);
        apply_rx(sr, si, 3 - w, cs, sn);
    }

#pragma unroll
    for (int d = 0; d < 2; ++d) {
#pragma unroll
        for (int w = 0; w < 4; ++w) {
            const int base = d * 12 + w * 3;
            apply_rx(sr, si, 3 - w, gc[base + 0], gs[base + 0]);
            apply_ry(sr, si, 3 - w, gc[base + 1], gs[base + 1]);
            apply_rz(sr, si, 3 - w, gc[base + 2], gs[base + 2]);
        }
        apply_cnot(sr, si, 0, 1);
        apply_cnot(sr, si, 1, 2);
        apply_cnot(sr, si, 2, 3);
        apply_cnot(sr, si, 3, 0);
    }

    // ---- probabilities and Z expectations ----
    float pr16[16];
#pragma unroll
    for (int i = 0; i < 16; ++i) pr16[i] = sr[i] * sr[i] + si[i] * si[i];

    float z[4];
#pragma unroll
    for (int w = 0; w < 4; ++w) {
        const int bit = 3 - w;
        float acc = 0.0f;
#pragma unroll
        for (int i = 0; i < 16; ++i)
            acc += ((i >> bit) & 1) ? -pr16[i] : pr16[i];
        z[w] = acc;
    }

    // ---- block reduction: sum(z), sum(z^2) -> per-block partials ----
    float vals[8] = {z[0], z[1], z[2], z[3],
                     z[0] * z[0], z[1] * z[1], z[2] * z[2], z[3] * z[3]};
#pragma unroll
    for (int j = 0; j < 8; ++j) {
        float v = vals[j];
#pragma unroll
        for (int off = 32; off >= 1; off >>= 1)
            v += __shfl_down(v, off, 64);
        if ((t & 63) == 0) red[(t >> 6) * 8 + j] = v;
    }
    __syncthreads();
    if (t < 8)
        partials[blockIdx.x * 8 + t] = red[t] + red[8 + t] + red[16 + t] + red[24 + t];

    // ---- grid-wide sync: partials visible device-wide; z stays in registers ----
    __threadfence();
    cg::this_grid().sync();

    // ---- every block redundantly reduces partials (8 KB from L2) ----
    if (t < 64) {
        float part[8];
#pragma unroll
        for (int j = 0; j < 8; ++j) part[j] = 0.0f;
        for (int r = t; r < (int)gridDim.x; r += 64) {
            const float* row = partials + r * 8;
#pragma unroll
            for (int j = 0; j < 8; ++j) part[j] += row[j];
        }
#pragma unroll
        for (int j = 0; j < 8; ++j) {
            float v = part[j];
#pragma unroll
            for (int off = 32; off >= 1; off >>= 1)
                v += __shfl_down(v, off, 64);
            if (t == 0) stats[j] = v;
        }
    }
    __syncthreads();

    // ---- BN finalize on register-resident z, single coalesced store ----
    const float invB = 1.0f / (float)B;
    float res[4];
#pragma unroll
    for (int i = 0; i < 4; ++i) {
        const float mean = stats[i] * invB;
        float var = stats[4 + i] * invB - mean * mean;
        var = fmaxf(var, 0.0f);
        const float scale = gamma[i] * rsqrtf(var + 1e-5f);
        res[i] = (z[i] - mean) * scale + beta[i];
    }
    out[s] = make_float4(res[0], res[1], res[2], res[3]);
}

// ---------------- launch ----------------
extern "C" void kernel_launch(void* const* d_in, const int* in_sizes, int n_in,
                              void* d_out, int out_size, void* d_ws, size_t ws_size,
                              hipStream_t stream) {
    const float4* x = (const float4*)d_in[0];
    const float* enc_w = (const float*)d_in[1];
    const float* enc_b = (const float*)d_in[2];
    const float* var_params = (const float*)d_in[3];
    const float* gamma = (const float*)d_in[4];
    const float* beta = (const float*)d_in[5];

    int B = in_sizes[0] / 576;                  // 65536
    float4* out = (float4*)d_out;
    float* partials = (float*)d_ws;             // nBlocks*8 floats = 8 KB

    int nBlocks = B / 256;                      // 256 -> 1 block/CU, co-resident

    void* args[] = {(void*)&x, (void*)&enc_w, (void*)&enc_b, (void*)&var_params,
                    (void*)&gamma, (void*)&beta, (void*)&out, (void*)&partials,
                    (void*)&B};
    hipLaunchCooperativeKernel((const void*)fused_kernel, dim3(nBlocks), dim3(256),
                               args, 0, stream);
}

// Round 3
// 237.623 us; speedup vs baseline: 1.2434x; 1.2434x over previous
//
#include <hip/hip_runtime.h>
#include <hip/hip_cooperative_groups.h>

namespace cg = cooperative_groups;

// ---------------- quantum gate appliers (16-amp statevector in regs) ----------------
// wire w -> bit position (3 - w); bit 3 is MSB of the flat index (row-major reshape).

__device__ __forceinline__ void apply_rx(float* sr, float* si, int bit, float c, float s) {
    const int m = 1 << bit;
#pragma unroll
    for (int idx = 0; idx < 16; ++idx) {
        if (idx & m) continue;
        const int j = idx | m;
        float a0r = sr[idx], a0i = si[idx], a1r = sr[j], a1i = si[j];
        // U = [[c, -i s], [-i s, c]]
        sr[idx] = c * a0r + s * a1i;
        si[idx] = c * a0i - s * a1r;
        sr[j]   = c * a1r + s * a0i;
        si[j]   = c * a1i - s * a0r;
    }
}

__device__ __forceinline__ void apply_ry(float* sr, float* si, int bit, float c, float s) {
    const int m = 1 << bit;
#pragma unroll
    for (int idx = 0; idx < 16; ++idx) {
        if (idx & m) continue;
        const int j = idx | m;
        float a0r = sr[idx], a0i = si[idx], a1r = sr[j], a1i = si[j];
        // U = [[c, -s], [s, c]]
        sr[idx] = c * a0r - s * a1r;
        si[idx] = c * a0i - s * a1i;
        sr[j]   = s * a0r + c * a1r;
        si[j]   = s * a0i + c * a1i;
    }
}

__device__ __forceinline__ void apply_rz(float* sr, float* si, int bit, float c, float s) {
    const int m = 1 << bit;
#pragma unroll
    for (int idx = 0; idx < 16; ++idx) {
        if (idx & m) continue;
        const int j = idx | m;
        float a0r = sr[idx], a0i = si[idx], a1r = sr[j], a1i = si[j];
        // diag(e^{-i t/2}, e^{+i t/2}) ; c = cos(t/2), s = sin(t/2)
        sr[idx] = c * a0r + s * a0i;
        si[idx] = c * a0i - s * a0r;
        sr[j]   = c * a1r - s * a1i;
        si[j]   = c * a1i + s * a1r;
    }
}

__device__ __forceinline__ void apply_cnot(float* sr, float* si, int cw, int tw) {
    const int cb = 3 - cw, tb = 3 - tw;
#pragma unroll
    for (int idx = 0; idx < 16; ++idx) {
        if (((idx >> cb) & 1) && !((idx >> tb) & 1)) {
            const int j = idx | (1 << tb);
            float tr = sr[idx]; sr[idx] = sr[j]; sr[j] = tr;
            float ti = si[idx]; si[idx] = si[j]; si[j] = ti;
        }
    }
}

// ---------------- per-thread: pool-row q of sample s -> angles (4-lane butterfly) -> circuit -> z[4]
// Thread q of a 4-lane group streams the sample's pool-row q = image rows [6q, 6q+6)
// = 36 contiguous float4. Pool-cell index ((4j+c)%24)/6 is COMPILE-TIME (no scratch).
// All 4 lanes end with the full angles via shfl_xor butterfly and compute the circuit
// redundantly (branch-free; circuit is tiny vs the memory stream).

__device__ __forceinline__ void pool_circuit(
    const float4* __restrict__ x,
    const float* __restrict__ enc_w,
    const float* __restrict__ enc_b,
    const float* __restrict__ var_params,
    int s, int q, float z[4])
{
    float pacc[4] = {0.0f, 0.0f, 0.0f, 0.0f};
    const float4* xs = x + (size_t)s * 144 + q * 36;
#pragma unroll
    for (int j = 0; j < 36; ++j) {
        const float4 v = xs[j];
        pacc[((4 * j + 0) % 24) / 6] += v.x;
        pacc[((4 * j + 1) % 24) / 6] += v.y;
        pacc[((4 * j + 2) % 24) / 6] += v.z;
        pacc[((4 * j + 3) % 24) / 6] += v.w;
    }

    // partial angles from this thread's 4 pool cells (k = 4q + pc)
    float pa[4];
#pragma unroll
    for (int i = 0; i < 4; ++i) {
        const float* wr = enc_w + i * 16 + q * 4;
        pa[i] = (wr[0] * pacc[0] + wr[1] * pacc[1] +
                 wr[2] * pacc[2] + wr[3] * pacc[3]) * (1.0f / 36.0f);
    }
    float av[4];
#pragma unroll
    for (int i = 0; i < 4; ++i) {
        float v = pa[i];
        v += __shfl_xor(v, 1, 64);
        v += __shfl_xor(v, 2, 64);
        av[i] = v + enc_b[i];
    }

    // gate tables (uniform params; sincos in VALU, registers)
    float gc[24], gs[24];
#pragma unroll
    for (int i = 0; i < 24; ++i) {
        float sn, cs;
        __sincosf(0.5f * var_params[i], &sn, &cs);
        gc[i] = cs; gs[i] = sn;
    }

    // statevector simulation, all in registers
    float sr[16], si[16];
#pragma unroll
    for (int i = 0; i < 16; ++i) { sr[i] = 0.0f; si[i] = 0.0f; }
    sr[0] = 1.0f;

#pragma unroll
    for (int w = 0; w < 4; ++w) {
        float sn, cs;
        __sincosf(0.5f * av[w], &sn, &cs);
        apply_rx(sr, si, 3 - w, cs, sn);
    }

#pragma unroll
    for (int d = 0; d < 2; ++d) {
#pragma unroll
        for (int w = 0; w < 4; ++w) {
            const int base = d * 12 + w * 3;
            apply_rx(sr, si, 3 - w, gc[base + 0], gs[base + 0]);
            apply_ry(sr, si, 3 - w, gc[base + 1], gs[base + 1]);
            apply_rz(sr, si, 3 - w, gc[base + 2], gs[base + 2]);
        }
        apply_cnot(sr, si, 0, 1);
        apply_cnot(sr, si, 1, 2);
        apply_cnot(sr, si, 2, 3);
        apply_cnot(sr, si, 3, 0);
    }

    float pr16[16];
#pragma unroll
    for (int i = 0; i < 16; ++i) pr16[i] = sr[i] * sr[i] + si[i] * si[i];

#pragma unroll
    for (int w = 0; w < 4; ++w) {
        const int bit = 3 - w;
        float acc = 0.0f;
#pragma unroll
        for (int i = 0; i < 16; ++i)
            acc += ((i >> bit) & 1) ? -pr16[i] : pr16[i];
        z[w] = acc;
    }
}

// ---------------- block partials: sum(z), sum(z^2); every lane holds z (x4 redundant) ----------------
__device__ __forceinline__ void block_partials(const float z[4], float* red /*[4*8]*/,
                                               float* __restrict__ partials, int t)
{
    float vals[8] = {z[0], z[1], z[2], z[3],
                     z[0] * z[0], z[1] * z[1], z[2] * z[2], z[3] * z[3]};
#pragma unroll
    for (int j = 0; j < 8; ++j) {
        float v = vals[j];
#pragma unroll
        for (int off = 32; off >= 1; off >>= 1)
            v += __shfl_down(v, off, 64);
        if ((t & 63) == 0) red[(t >> 6) * 8 + j] = v;
    }
    __syncthreads();
    if (t < 8)
        partials[blockIdx.x * 8 + t] =
            0.25f * (red[t] + red[8 + t] + red[16 + t] + red[24 + t]);  // /4 redundancy
}

// ---------------- cooperative single-pass kernel (preferred path) ----------------
// 1024 blocks x 256 threads, 4 threads/sample -> 4 blocks/CU = 16 waves/CU.
__global__ __launch_bounds__(256, 4) void fused_coop(
    const float4* __restrict__ x,
    const float* __restrict__ enc_w, const float* __restrict__ enc_b,
    const float* __restrict__ var_params,
    const float* __restrict__ gamma, const float* __restrict__ beta,
    float* __restrict__ out,          // [B*4] fp32 (= d_out)
    float* __restrict__ partials,     // [gridDim.x * 8]
    int B)
{
    __shared__ float red[4 * 8];
    __shared__ float stats[8];

    const int t = threadIdx.x;
    const int s = blockIdx.x * 64 + (t >> 2);
    const int q = t & 3;

    float z[4];
    pool_circuit(x, enc_w, enc_b, var_params, s, q, z);
    block_partials(z, red, partials, t);

    __threadfence();
    cg::this_grid().sync();

    // every block redundantly reduces partials (32 KB, L2)
    const int nRows = (int)gridDim.x;
    if (t < 64) {
        float part[8] = {0, 0, 0, 0, 0, 0, 0, 0};
        for (int r = t; r < nRows; r += 64) {
            const float* row = partials + r * 8;
#pragma unroll
            for (int j = 0; j < 8; ++j) part[j] += row[j];
        }
#pragma unroll
        for (int j = 0; j < 8; ++j) {
            float v = part[j];
#pragma unroll
            for (int off = 32; off >= 1; off >>= 1)
                v += __shfl_down(v, off, 64);
            if (t == 0) stats[j] = v;
        }
    }
    __syncthreads();

    // BN on register-resident z; lane q writes component q -> fully coalesced
    const float invB = 1.0f / (float)B;
    const float mean = stats[q] * invB;
    float var = stats[4 + q] * invB - mean * mean;
    var = fmaxf(var, 0.0f);
    const float scale = gamma[q] * rsqrtf(var + 1e-5f);
    out[blockIdx.x * 256 + t] = (z[q] - mean) * scale + beta[q];
}

// ---------------- fallback path: fused (pool+circuit+partials) then tiny BN kernel ----------------
__global__ __launch_bounds__(256, 4) void fused_split(
    const float4* __restrict__ x,
    const float* __restrict__ enc_w, const float* __restrict__ enc_b,
    const float* __restrict__ var_params,
    float* __restrict__ out_z,        // [B*4] fp32 z (= d_out, in place for BN)
    float* __restrict__ partials)     // [gridDim.x * 8]
{
    __shared__ float red[4 * 8];
    const int t = threadIdx.x;
    const int s = blockIdx.x * 64 + (t >> 2);
    const int q = t & 3;

    float z[4];
    pool_circuit(x, enc_w, enc_b, var_params, s, q, z);
    out_z[blockIdx.x * 256 + t] = z[q];         // coalesced
    block_partials(z, red, partials, t);
}

__global__ __launch_bounds__(256) void bn_kernel(
    float4* __restrict__ io,                // [B] fp32 z quads -> out quads (= d_out)
    const float* __restrict__ partials,     // [nPartialRows * 8]
    const float* __restrict__ gamma,
    const float* __restrict__ beta,
    int nPartialRows, int B)
{
    __shared__ float stats[8];
    const int t = threadIdx.x;

    if (t < 64) {
        float part[8];
#pragma unroll
        for (int j = 0; j < 8; ++j) part[j] = 0.0f;
        for (int r = t; r < nPartialRows; r += 64) {
            const float* row = partials + r * 8;
#pragma unroll
            for (int j = 0; j < 8; ++j) part[j] += row[j];
        }
#pragma unroll
        for (int j = 0; j < 8; ++j) {
            float v = part[j];
#pragma unroll
            for (int off = 32; off >= 1; off >>= 1)
                v += __shfl_down(v, off, 64);
            if (t == 0) stats[j] = v;
        }
    }
    __syncthreads();

    const int b = blockIdx.x * 256 + t;
    const float invB = 1.0f / (float)B;
    const float4 z4 = io[b];
    const float zz[4] = {z4.x, z4.y, z4.z, z4.w};

    float res[4];
#pragma unroll
    for (int i = 0; i < 4; ++i) {
        const float mean = stats[i] * invB;
        float var = stats[4 + i] * invB - mean * mean;
        var = fmaxf(var, 0.0f);
        const float scale = gamma[i] * rsqrtf(var + 1e-5f);
        res[i] = (zz[i] - mean) * scale + beta[i];
    }
    io[b] = make_float4(res[0], res[1], res[2], res[3]);
}

// ---------------- launch ----------------
extern "C" void kernel_launch(void* const* d_in, const int* in_sizes, int n_in,
                              void* d_out, int out_size, void* d_ws, size_t ws_size,
                              hipStream_t stream) {
    const float4* x = (const float4*)d_in[0];
    const float* enc_w = (const float*)d_in[1];
    const float* enc_b = (const float*)d_in[2];
    const float* var_params = (const float*)d_in[3];
    const float* gamma = (const float*)d_in[4];
    const float* beta = (const float*)d_in[5];

    int B = in_sizes[0] / 576;                  // 65536
    float* out = (float*)d_out;
    float* partials = (float*)d_ws;             // nBlocks*8 floats = 32 KB

    const int nBlocks = B / 64;                 // 1024 -> 4 blocks/CU target

    // one-time co-residency check for the cooperative path (host query, graph-safe)
    static int mode = -1;
    if (mode < 0) {
        int maxActive = 0;
        hipError_t e = hipOccupancyMaxActiveBlocksPerMultiprocessor(
            &maxActive, fused_coop, 256, 0);
        int numCU = 0;
        hipDeviceGetAttribute(&numCU, hipDeviceAttributeMultiprocessorCount, 0);
        mode = (e == hipSuccess && numCU > 0 && maxActive * numCU >= nBlocks) ? 1 : 0;
    }

    if (mode == 1) {
        void* args[] = {(void*)&x, (void*)&enc_w, (void*)&enc_b, (void*)&var_params,
                        (void*)&gamma, (void*)&beta, (void*)&out, (void*)&partials,
                        (void*)&B};
        hipLaunchCooperativeKernel((const void*)fused_coop, dim3(nBlocks), dim3(256),
                                   args, 0, stream);
    } else {
        fused_split<<<nBlocks, 256, 0, stream>>>(x, enc_w, enc_b, var_params,
                                                 out, partials);
        bn_kernel<<<B / 256, 256, 0, stream>>>((float4*)out, partials, gamma, beta,
                                               nBlocks, B);
    }
}